// Round 9
// baseline (663.096 us; speedup 1.0000x reference)
//
#include <hip/hip_runtime.h>

#define NN 50000
#define DD 256
#define HH 8
#define EE 500000
#define INV_SQRT_DK 0.17677669529663687f

typedef __attribute__((ext_vector_type(8))) short bf16x8;   // 8 bf16 = 4 VGPRs
typedef __attribute__((ext_vector_type(4))) float f32x4;

__device__ __forceinline__ unsigned short f2bf(float f) {
    unsigned int u = __float_as_uint(f);
    u = (u + 0x7FFFu + ((u >> 16) & 1u)) >> 16;   // round-to-nearest-even
    return (unsigned short)u;
}
__device__ __forceinline__ float bf2f(unsigned short u) {
    return __uint_as_float(((unsigned int)u) << 16);
}
__device__ __forceinline__ float bflo(unsigned int u) {     // low bf16 of dword
    return __uint_as_float(u << 16);
}
__device__ __forceinline__ float bfhi(unsigned int u) {     // high bf16 of dword
    return __uint_as_float(u & 0xFFFF0000u);
}
__device__ __forceinline__ bf16x8 pack8(float4 lo, float4 hi) {
    bf16x8 v;
    v[0] = (short)f2bf(lo.x); v[1] = (short)f2bf(lo.y);
    v[2] = (short)f2bf(lo.z); v[3] = (short)f2bf(lo.w);
    v[4] = (short)f2bf(hi.x); v[5] = (short)f2bf(hi.y);
    v[6] = (short)f2bf(hi.z); v[7] = (short)f2bf(hi.w);
    return v;
}

// ---------------------------------------------------------------------------
// MERGED prep: weight transforms (blocks 0..2055 = 257*8) + degree histogram
// (blocks 2056..5963).  cnt must be zeroed beforehand.
// y in [0,4): fused per-head transform -> permuted-transposed bf16 weight +
//   fp32 eff-bias (interleaved KV layout: K col j -> row (j>>2)*8+(j&3), V +4).
// y in [4,8): plain transpose+bf16 (Wq -> BT rows 512..767, Wa -> WaT), bq -> beff.
__global__ __launch_bounds__(256) void prep_kernel(const float* __restrict__ Wk_u, const float* __restrict__ bk_u,
                                                   const float* __restrict__ att_ui_,
                                                   const float* __restrict__ Wv_u, const float* __restrict__ bv_u,
                                                   const float* __restrict__ msg_ui_,
                                                   const float* __restrict__ Wk_i, const float* __restrict__ bk_i,
                                                   const float* __restrict__ att_iu_,
                                                   const float* __restrict__ Wv_i, const float* __restrict__ bv_i,
                                                   const float* __restrict__ msg_iu_,
                                                   const float* __restrict__ Wq_u, const float* __restrict__ bq_u,
                                                   const float* __restrict__ Wq_i, const float* __restrict__ bq_i,
                                                   const float* __restrict__ Wa_u, const float* __restrict__ Wa_i,
                                                   unsigned short* __restrict__ BTu, float* __restrict__ beffU,
                                                   unsigned short* __restrict__ BTi, float* __restrict__ beffI,
                                                   unsigned short* __restrict__ WaTu, unsigned short* __restrict__ WaTi,
                                                   const int* __restrict__ dst_ui, const int* __restrict__ dst_iu,
                                                   int* __restrict__ cnt) {
    int blk = blockIdx.x;
    if (blk >= 2056) {
        int e = (blk - 2056) * 256 + threadIdx.x;
        if (e < EE) atomicAdd(&cnt[dst_ui[e]], 1);
        else if (e < 2 * EE) atomicAdd(&cnt[NN + dst_iu[e - EE]], 1);
        return;
    }
    int y = blk / 257, x = blk % 257;
    if (y < 4) {
        const float* W = (y == 0) ? Wk_u : (y == 1) ? Wv_u : (y == 2) ? Wk_i : Wv_i;
        const float* b = (y == 0) ? bk_u : (y == 1) ? bv_u : (y == 2) ? bk_i : bv_i;
        const float* T = (y == 0) ? att_ui_ : (y == 1) ? msg_ui_ : (y == 2) ? att_iu_ : msg_iu_;
        unsigned short* WT = (y < 2) ? BTu : BTi;
        float* be = (y < 2) ? beffU : beffI;
        int j = threadIdx.x;
        int h = j >> 5, jj = j & 31;
        int pj = ((j >> 2) << 3) + (j & 3) + ((y & 1) ? 4 : 0);   // interleaved KV row
        const float* Th = T + h * 1024;
        if (x < 256) {
            int c = x;
            float acc = 0.f;
            #pragma unroll 8
            for (int i = 0; i < 32; ++i) acc += W[c * 256 + h * 32 + i] * Th[i * 32 + jj];
            WT[pj * 256 + c] = f2bf(acc);
        } else {
            float acc = 0.f;
            #pragma unroll 8
            for (int i = 0; i < 32; ++i) acc += b[h * 32 + i] * Th[i * 32 + jj];
            be[pj] = acc;
        }
    } else if (x < 256) {
        int yy = y - 4;
        const float* W = (yy == 0) ? Wq_u : (yy == 1) ? Wq_i : (yy == 2) ? Wa_u : Wa_i;
        unsigned short* WT = (yy == 0) ? BTu + 512 * 256 : (yy == 1) ? BTi + 512 * 256 : (yy == 2) ? WaTu : WaTi;
        int k = x, n = threadIdx.x;
        WT[n * 256 + k] = f2bf(W[k * 256 + n]);
        if (k == 0 && yy < 2) {
            float* be = (yy == 0) ? beffU : beffI;
            const float* bq = (yy == 0) ? bq_u : bq_i;
            be[512 + n] = bq[n];
        }
    }
}

// ---------------------------------------------------------------------------
__global__ __launch_bounds__(256) void alloc_kernel(const int* __restrict__ cnt,
                                                    int* __restrict__ start,
                                                    int* __restrict__ ctr) {
    int y = blockIdx.y;
    int i = blockIdx.x * 256 + threadIdx.x;
    int idx = y * NN + i;
    int v = (i < NN) ? cnt[idx] : 0;
    int lane = threadIdx.x & 63;
    int pre = v;
    #pragma unroll
    for (int o = 1; o < 64; o <<= 1) {
        int u = __shfl_up(pre, o, 64);
        if (lane >= o) pre += u;
    }
    int wsum = __shfl(pre, 63, 64);
    int base = 0;
    if (lane == 63) base = atomicAdd(&ctr[y], wsum);
    base = __shfl(base, 63, 64);
    if (i < NN) start[idx] = y * EE + base + pre - v;
}

__global__ void scatter_kernel(const int* __restrict__ dst_ui, const int* __restrict__ src_ui,
                               const int* __restrict__ dst_iu, const int* __restrict__ src_iu,
                               const int* __restrict__ start, int* __restrict__ cur,
                               unsigned short* __restrict__ srcid) {
    int e = blockIdx.x * blockDim.x + threadIdx.x;
    int d, s;
    if (e < EE) { d = dst_ui[e]; s = src_ui[e]; }
    else if (e < 2 * EE) { d = NN + dst_iu[e - EE]; s = src_iu[e - EE]; }
    else return;
    int pos = start[d] + atomicAdd(&cur[d], 1);
    srcid[pos] = (unsigned short)s;
}

// ---------------------------------------------------------------------------
// C[M,768] = bf16(H_f32[M,256]) @ BT_bf16 + beff.  fp32->bf16 conversion of A
// is FUSED into staging (pack8 at ds_write) -- the standalone conv kernel is
// gone.  BT rows 0..511 pre-permuted -> cols 0..511 ARE the interleaved KV
// layout.  DEPTH-2 PIPELINE: two named register sets alternate; the set
// written to LDS at iter k was loaded at iter k-2 (~2 iters of HBM-latency
// cover).  One barrier per K-step.  1D grid 4692, bijective XCD swizzle
// (m204), bn fastest -> A-panel sharers on the same XCD/L2.
// Epilogue: two 64-row halves staged via LDS (stride 136), ushort8 stores.
__global__ __launch_bounds__(256) void gemm_kvq(const float* __restrict__ Hu,
                                                const float* __restrict__ Hi,
                                                const unsigned short* __restrict__ BTu,
                                                const unsigned short* __restrict__ BTi,
                                                const float* __restrict__ beffU,
                                                const float* __restrict__ beffI,
                                                unsigned short* __restrict__ KVu,
                                                unsigned short* __restrict__ KVi,
                                                unsigned short* __restrict__ Qu,
                                                unsigned short* __restrict__ Qi) {
    __shared__ __align__(16) char smem[40960];   // 2 x (As 10240 | Bs 10240); epilogue reuses
    bf16x8* As0 = (bf16x8*)smem;
    bf16x8* Bs0 = (bf16x8*)(smem + 10240);
    bf16x8* As1 = (bf16x8*)(smem + 20480);
    bf16x8* Bs1 = (bf16x8*)(smem + 30720);
    // ---- XCD-bijective swizzle: nwg = 4692 = 8*586 + 4 ----
    int bsw = blockIdx.x;
    int xcd = bsw & 7, sidx = bsw >> 3;
    int wg = (xcd < 4 ? xcd * 587 : 2348 + (xcd - 4) * 586) + sidx;
    int bni = wg % 6; int rest = wg / 6;
    int bmi = rest % 391; int z = rest / 391;
    const float* H = z ? Hi : Hu;
    const unsigned short* BT = z ? BTi : BTu;
    const float* beff = z ? beffI : beffU;
    unsigned short* KV = z ? KVi : KVu;
    unsigned short* Qb = z ? Qi : Qu;
    int bm = bmi * 128, bn = bni * 128;
    int tid = threadIdx.x;
    int lane = tid & 63, w = tid >> 6;
    int wm = (w & 1) * 64, wn = (w >> 1) * 64;
    int m16 = lane & 15, q = lane >> 4;

    // staging geometry: thread covers (row0, off) and (row1 = row0+64, off)
    int row0 = tid >> 2, off = tid & 3;
    int row1 = row0 + 64;
    int gr0 = bm + row0, gr1 = bm + row1;
    const bool val0 = gr0 < NN, val1 = gr1 < NN;
    const float* pA0 = &H[(size_t)gr0 * 256 + off * 8];
    const float* pA1 = &H[(size_t)gr1 * 256 + off * 8];
    const unsigned short* pB0 = &BT[(size_t)(bn + row0) * 256 + off * 8];
    const unsigned short* pB1 = &BT[(size_t)(bn + row1) * 256 + off * 8];

    f32x4 acc[4][4] = {};
    const float4 zf = {0.f, 0.f, 0.f, 0.f};
    // two staging register sets (fp32 A + bf16 B), alternating per iteration
    float4 Al0A, Ah0A, Al1A, Ah1A; bf16x8 B0A, B1A;
    float4 Al0B, Ah0B, Al1B, Ah1B; bf16x8 B0B, B1B;

#define LDA(S, kt) { \
        Al0##S = zf; Ah0##S = zf; Al1##S = zf; Ah1##S = zf; \
        if (val0) { Al0##S = *(const float4*)(pA0 + (kt) * 32); \
                    Ah0##S = *(const float4*)(pA0 + (kt) * 32 + 4); } \
        if (val1) { Al1##S = *(const float4*)(pA1 + (kt) * 32); \
                    Ah1##S = *(const float4*)(pA1 + (kt) * 32 + 4); } \
        B0##S = *(const bf16x8*)(pB0 + (kt) * 32); \
        B1##S = *(const bf16x8*)(pB1 + (kt) * 32); }

#define WRS(Adst, Bdst, S) { \
        Adst[row0 * 5 + off] = pack8(Al0##S, Ah0##S); \
        Adst[row1 * 5 + off] = pack8(Al1##S, Ah1##S); \
        Bdst[row0 * 5 + off] = B0##S; \
        Bdst[row1 * 5 + off] = B1##S; }

#define ITER(ks, S) { \
        bf16x8* Ac = ((ks) & 1) ? As1 : As0; \
        bf16x8* Bc = ((ks) & 1) ? Bs1 : Bs0; \
        if ((ks) < 7) { \
            bf16x8* An = ((ks) & 1) ? As0 : As1; \
            bf16x8* Bn = ((ks) & 1) ? Bs0 : Bs1; \
            WRS(An, Bn, S); \
        } \
        if ((ks) < 5) LDA(S, (ks) + 3); \
        bf16x8 af[4], bfr[4]; \
        _Pragma("unroll") \
        for (int i = 0; i < 4; ++i) af[i] = Ac[(wm + 16 * i + m16) * 5 + q]; \
        _Pragma("unroll") \
        for (int j = 0; j < 4; ++j) bfr[j] = Bc[(wn + 16 * j + m16) * 5 + q]; \
        _Pragma("unroll") \
        for (int i = 0; i < 4; ++i) \
            _Pragma("unroll") \
            for (int j = 0; j < 4; ++j) \
                acc[i][j] = __builtin_amdgcn_mfma_f32_16x16x32_bf16(af[i], bfr[j], acc[i][j], 0, 0, 0); \
        __syncthreads(); }

    // prologue: tile 0 -> LDS0 (via set A), then set A <- t1, set B <- t2
    LDA(A, 0)
    WRS(As0, Bs0, A)
    LDA(A, 1)
    LDA(B, 2)
    __syncthreads();
    ITER(0, A) ITER(1, B) ITER(2, A) ITER(3, B)
    ITER(4, A) ITER(5, B) ITER(6, A) ITER(7, B)
#undef LDA
#undef WRS
#undef ITER

    // ---- epilogue: two 64-row halves staged via LDS, coalesced 16B stores ----
    const bool isKV = (bn < 512);
    unsigned short* dstb = isKV ? KV : Qb;
    const int rowlen = isKV ? 512 : 256;
    const int coloff = isKV ? bn : (bn - 512);
    unsigned short* Cs = (unsigned short*)smem;   // 64*136 = 8704 ushorts = 17408B
    #pragma unroll
    for (int half = 0; half < 2; ++half) {
        if ((w & 1) == half) {                    // waves owning rows [half*64, half*64+64)
            #pragma unroll
            for (int i = 0; i < 4; ++i) {
                int rloc = 16 * i + q * 4;        // local row within half (wm == half*64)
                #pragma unroll
                for (int j = 0; j < 4; ++j) {
                    int cl = wn + 16 * j + m16;
                    float bv = beff[bn + cl];
                    #pragma unroll
                    for (int r = 0; r < 4; ++r)
                        Cs[(rloc + r) * 136 + cl] = f2bf(acc[i][j][r] + bv);
                }
            }
        }
        __syncthreads();
        #pragma unroll
        for (int it = 0; it < 4; ++it) {
            int idx = it * 256 + tid;
            int row = idx >> 4, seg = idx & 15;
            int gr = bm + half * 64 + row;
            if (gr < NN) {
                bf16x8 v = *(const bf16x8*)&Cs[row * 136 + seg * 8];
                *(bf16x8*)&dstb[(size_t)gr * rowlen + coloff + seg * 8] = v;
            }
        }
        __syncthreads();
    }
}

// ---------------------------------------------------------------------------
// FUSED out-projection + skip-gate + layernorm.
// C[128,256] = A_bf16 @ WaT + ba; out = LN(C*alpha + h*(1-alpha)).
// 512 threads = 8 waves; wave w owns rows [16w,16w+16) x ALL 256 cols.
// grid (391, 2): y = ntype (0 user -> out[0], 1 item -> out[ND]).
__global__ __launch_bounds__(512) void gemm_ln(const unsigned short* __restrict__ A0,
                                               const unsigned short* __restrict__ A1,
                                               const unsigned short* __restrict__ BT0,
                                               const unsigned short* __restrict__ BT1,
                                               const float* __restrict__ ba0,
                                               const float* __restrict__ ba1,
                                               const float* __restrict__ h0,
                                               const float* __restrict__ h1,
                                               const float* __restrict__ skp0,
                                               const float* __restrict__ skp1,
                                               const float* __restrict__ g0, const float* __restrict__ be0,
                                               const float* __restrict__ g1, const float* __restrict__ be1,
                                               float* __restrict__ out) {
    __shared__ __align__(16) char smem[33280];   // staging 30720B | epilogue 32*260*4B
    bf16x8* As = (bf16x8*)smem;                  // 128*5 entries = 10240B
    bf16x8* Bs = (bf16x8*)(smem + 10240);        // 256*5 entries = 20480B
    float* Es = (float*)smem;                    // epilogue: [32][260]
    int z = blockIdx.y;
    const unsigned short* A = z ? A1 : A0;
    const unsigned short* BT = z ? BT1 : BT0;
    const float* ba = z ? ba1 : ba0;
    const float* hb = z ? h1 : h0;
    const float* skp = z ? skp1 : skp0;
    const float* g = z ? g1 : g0;
    const float* bb = z ? be1 : be0;
    float* o = out + (z ? (size_t)NN * DD : 0);

    int bm = blockIdx.x * 128;
    int tid = threadIdx.x;
    int lane = tid & 63, w = tid >> 6;           // w in [0,8)
    int m16 = lane & 15, q = lane >> 4;
    f32x4 acc[16] = {};
    for (int k0 = 0; k0 < 256; k0 += 32) {
        {   // A: 128 rows x 4 chunks -> one vec8 per thread
            int row = tid >> 2, ch = tid & 3;
            int gr = bm + row;
            bf16x8 va = {};
            if (gr < NN) va = *(const bf16x8*)&A[(size_t)gr * 256 + k0 + ch * 8];
            As[row * 5 + ch] = va;
        }
        #pragma unroll
        for (int cc = 0; cc < 2; ++cc) {         // B: 256 rows x 4 chunks -> two per thread
            int idx = tid + cc * 512;
            int n = idx >> 2, ch = idx & 3;
            Bs[n * 5 + ch] = *(const bf16x8*)&BT[(size_t)n * 256 + k0 + ch * 8];
        }
        __syncthreads();
        bf16x8 af = As[(w * 16 + m16) * 5 + q];
        #pragma unroll
        for (int jh = 0; jh < 2; ++jh) {
            bf16x8 bfr[8];
            #pragma unroll
            for (int jj = 0; jj < 8; ++jj) bfr[jj] = Bs[((jh * 8 + jj) * 16 + m16) * 5 + q];
            #pragma unroll
            for (int jj = 0; jj < 8; ++jj)
                acc[jh * 8 + jj] = __builtin_amdgcn_mfma_f32_16x16x32_bf16(af, bfr[jj], acc[jh * 8 + jj], 0, 0, 0);
        }
        __syncthreads();
    }
    // ---- fused epilogue: 4 quarters of 32 rows ----
    float alpha = 1.f / (1.f + __expf(-skp[0]));
    float am1 = 1.f - alpha;
    float4 ba4 = *(const float4*)&ba[lane * 4];
    float4 g4 = *(const float4*)&g[lane * 4];
    float4 b4 = *(const float4*)&bb[lane * 4];
    #pragma unroll
    for (int p = 0; p < 4; ++p) {
        if ((w >> 1) == p) {                     // stage this quarter's acc (f32)
            int rbase = (w & 1) * 16 + 4 * q;
            #pragma unroll
            for (int j = 0; j < 16; ++j)
                #pragma unroll
                for (int rr = 0; rr < 4; ++rr)
                    Es[(rbase + rr) * 260 + 16 * j + m16] = acc[j][rr];
        }
        __syncthreads();
        #pragma unroll
        for (int rrr = 0; rrr < 4; ++rrr) {
            int lrow = w * 4 + rrr;              // 0..31
            int gr = bm + 32 * p + lrow;
            if (gr < NN) {
                float4 tm = *(const float4*)&Es[lrow * 260 + lane * 4];
                float4 hh = *(const float4*)&hb[(size_t)gr * 256 + lane * 4];
                float x0 = (tm.x + ba4.x) * alpha + hh.x * am1;
                float x1 = (tm.y + ba4.y) * alpha + hh.y * am1;
                float x2 = (tm.z + ba4.z) * alpha + hh.z * am1;
                float x3 = (tm.w + ba4.w) * alpha + hh.w * am1;
                float s = x0 + x1 + x2 + x3;
                #pragma unroll
                for (int off = 32; off > 0; off >>= 1) s += __shfl_xor(s, off, 64);
                float mean = s * (1.f / 256.f);
                float d0 = x0 - mean, d1 = x1 - mean, d2 = x2 - mean, d3 = x3 - mean;
                float s2 = d0 * d0 + d1 * d1 + d2 * d2 + d3 * d3;
                #pragma unroll
                for (int off = 32; off > 0; off >>= 1) s2 += __shfl_xor(s2, off, 64);
                float rstd = rsqrtf(s2 * (1.f / 256.f) + 1e-5f);
                float4 r;
                r.x = d0 * rstd * g4.x + b4.x;
                r.y = d1 * rstd * g4.y + b4.y;
                r.z = d2 * rstd * g4.z + b4.z;
                r.w = d3 * rstd * g4.w + b4.w;
                *(float4*)&o[(size_t)gr * 256 + lane * 4] = r;
            }
        }
        __syncthreads();
    }
}

// ---------------------------------------------------------------------------
// Fused score+softmax+aggregate, ONE WAVE per dst node, 4 elems per lane.
// srcid is ushort (src < 50000 < 65536).  Per 64-edge chunk, srcids come from
// one coalesced 2B/lane load (broadcast by __shfl); KV rows prefetched 4-deep
// into statically-indexed registers.
// grid 25000 x 256 (4 waves = 4 dst slots per block; slots >= NN are etype iu).
__global__ __launch_bounds__(256) void fused_agg(const int* __restrict__ start,
                                                 const int* __restrict__ cnt,
                                                 const unsigned short* __restrict__ srcid,
                                                 const unsigned short* __restrict__ Qi,
                                                 const unsigned short* __restrict__ Qu,
                                                 const unsigned short* __restrict__ KVu,
                                                 const unsigned short* __restrict__ KVi,
                                                 const float* __restrict__ pri_ui,
                                                 const float* __restrict__ pri_iu,
                                                 unsigned short* __restrict__ tI16,
                                                 unsigned short* __restrict__ tU16) {
    int w = threadIdx.x >> 6;
    int lane = threadIdx.x & 63;
    int b = blockIdx.x * 4 + w;
    bool second = (b >= NN);
    int d = second ? b - NN : b;
    const unsigned short* Q = second ? Qu : Qi;
    const unsigned short* KV = second ? KVi : KVu;
    const float* pri = second ? pri_iu : pri_ui;
    unsigned short* T = second ? tU16 : tI16;

    int h = lane >> 3;
    float sscale = pri[h] * INV_SQRT_DK;
    ushort4 q4 = *(const ushort4*)&Q[(size_t)d * 256 + lane * 4];
    float qx = bf2f(q4.x), qy = bf2f(q4.y), qz = bf2f(q4.z), qw = bf2f(q4.w);

    int p0 = start[b], n = cnt[b];
    float a0 = 0.f, a1 = 0.f, a2 = 0.f, a3 = 0.f, l = 0.f;

#define LDKV(idx) (*(const uint4*)&KV[(size_t)__shfl(myS, (idx), 64) * 512 + lane * 8])
#define PROC(kv) { \
        float sc = qx * bflo(kv.x) + qy * bfhi(kv.x) + qz * bflo(kv.y) + qw * bfhi(kv.y); \
        sc += __shfl_xor(sc, 1, 8); \
        sc += __shfl_xor(sc, 2, 8); \
        sc += __shfl_xor(sc, 4, 8); \
        float wgt = __expf(sc * sscale); \
        a0 += wgt * bflo(kv.z); \
        a1 += wgt * bfhi(kv.z); \
        a2 += wgt * bflo(kv.w); \
        a3 += wgt * bfhi(kv.w); \
        l += wgt; }

    for (int base = 0; base < n; base += 64) {
        int rem = n - base; if (rem > 64) rem = 64;
        int myS = (lane < rem) ? (int)srcid[p0 + base + lane] : 0;
        uint4 k0 = {}, k1 = {}, k2 = {}, k3 = {};
        if (0 < rem) k0 = LDKV(0);
        if (1 < rem) k1 = LDKV(1);
        if (2 < rem) k2 = LDKV(2);
        if (3 < rem) k3 = LDKV(3);
        int t = 0;
        for (; t + 4 <= rem; t += 4) {
            PROC(k0); if (t + 4 < rem) k0 = LDKV(t + 4);
            PROC(k1); if (t + 5 < rem) k1 = LDKV(t + 5);
            PROC(k2); if (t + 6 < rem) k2 = LDKV(t + 6);
            PROC(k3); if (t + 7 < rem) k3 = LDKV(t + 7);
        }
        if (t < rem)     PROC(k0);
        if (t + 1 < rem) PROC(k1);
        if (t + 2 < rem) PROC(k2);
    }
#undef LDKV
#undef PROC

    float inv = (l > 0.f) ? 1.f / l : 0.f;
    ushort4 o;
    o.x = f2bf(a0 * inv); o.y = f2bf(a1 * inv);
    o.z = f2bf(a2 * inv); o.w = f2bf(a3 * inv);
    *(ushort4*)&T[(size_t)d * 256 + lane * 4] = o;
}

// ---------------------------------------------------------------------------
extern "C" void kernel_launch(void* const* d_in, const int* in_sizes, int n_in,
                              void* d_out, int out_size, void* d_ws, size_t ws_size,
                              hipStream_t stream) {
    const float* h_user  = (const float*)d_in[0];
    const float* h_item  = (const float*)d_in[1];
    const int*   src_ui  = (const int*)d_in[2];
    const int*   dst_ui  = (const int*)d_in[3];
    const int*   src_iu  = (const int*)d_in[4];
    const int*   dst_iu  = (const int*)d_in[5];
    const float* Wk_user = (const float*)d_in[6];
    const float* bk_user = (const float*)d_in[7];
    const float* Wq_user = (const float*)d_in[8];
    const float* bq_user = (const float*)d_in[9];
    const float* Wv_user = (const float*)d_in[10];
    const float* bv_user = (const float*)d_in[11];
    const float* Wa_user = (const float*)d_in[12];
    const float* ba_user = (const float*)d_in[13];
    const float* ln_g_user = (const float*)d_in[14];
    const float* ln_b_user = (const float*)d_in[15];
    const float* skip_user = (const float*)d_in[16];
    const float* Wk_item = (const float*)d_in[17];
    const float* bk_item = (const float*)d_in[18];
    const float* Wq_item = (const float*)d_in[19];
    const float* bq_item = (const float*)d_in[20];
    const float* Wv_item = (const float*)d_in[21];
    const float* bv_item = (const float*)d_in[22];
    const float* Wa_item = (const float*)d_in[23];
    const float* ba_item = (const float*)d_in[24];
    const float* ln_g_item = (const float*)d_in[25];
    const float* ln_b_item = (const float*)d_in[26];
    const float* skip_item = (const float*)d_in[27];
    const float* pri_ui = (const float*)d_in[28];
    const float* att_ui = (const float*)d_in[29];
    const float* msg_ui = (const float*)d_in[30];
    const float* pri_iu = (const float*)d_in[31];
    const float* att_iu = (const float*)d_in[32];
    const float* msg_iu = (const float*)d_in[33];
    float* out = (float*)d_out;

    const size_t ND = (size_t)NN * DD;

    // ---- workspace carve (~210 MB, with aliasing) ----
    unsigned short* up = (unsigned short*)d_ws;
    unsigned short* KVu = up;  up += (size_t)NN * 512;   // interleaved K|V per user node
    unsigned short* KVi = up;  up += (size_t)NN * 512;
    unsigned short* Qu  = up;  up += ND;
    unsigned short* Qi  = up;  up += ND;
    unsigned short* tU16 = up; up += ND;                 // t-buffers (bf16)
    unsigned short* tI16 = up; up += ND;
    unsigned short* BTu = up;  up += 768 * 256;
    unsigned short* BTi = up;  up += 768 * 256;
    unsigned short* WaTu = up; up += 65536;
    unsigned short* WaTi = up; up += 65536;
    float* fp = (float*)up;
    float* beffU = fp; fp += 768;
    float* beffI = fp; fp += 768;
    int* ip = (int*)fp;
    int* cnt   = ip; ip += 2 * NN;     // cnt+cur+ctr contiguous: single memset
    int* cur   = ip; ip += 2 * NN;
    int* ctr   = ip; ip += 2;
    int* start = ip; ip += 2 * NN;
    unsigned short* srcid = (unsigned short*)ip;         // 2*EE ushorts = 2MB

    const int eb = (EE + 255) / 256;   // 1954

    // ---- prep: memset, weights+hist (merged), CSR ----
    hipMemsetAsync(cnt, 0, (4 * NN + 2) * sizeof(int), stream);
    prep_kernel<<<2056 + 2 * eb, 256, 0, stream>>>(Wk_user, bk_user, att_ui, Wv_user, bv_user, msg_ui,
                                                   Wk_item, bk_item, att_iu, Wv_item, bv_item, msg_iu,
                                                   Wq_user, bq_user, Wq_item, bq_item, Wa_user, Wa_item,
                                                   BTu, beffU, BTi, beffI, WaTu, WaTi,
                                                   dst_ui, dst_iu, cnt);
    alloc_kernel<<<dim3(196, 2), 256, 0, stream>>>(cnt, start, ctr);
    scatter_kernel<<<2 * eb, 256, 0, stream>>>(dst_ui, src_ui, dst_iu, src_iu, start, cur, srcid);

    // ---- projections: fp32 A direct (conv fused into staging), N=768 ----
    gemm_kvq<<<4692, 256, 0, stream>>>(h_user, h_item, BTu, BTi, beffU, beffI,
                                       KVu, KVi, Qu, Qi);

    // ---- fused edge-softmax aggregation, both etypes ----
    fused_agg<<<25000, 256, 0, stream>>>(start, cnt, srcid, Qi, Qu, KVu, KVi,
                                         pri_ui, pri_iu, tI16, tU16);

    // ---- FUSED out-projection + skip-gate + layernorm ----
    gemm_ln<<<dim3(391, 2), 512, 0, stream>>>(tU16, tI16, WaTu, WaTi, ba_user, ba_item,
                                              h_user, h_item, skip_user, skip_item,
                                              ln_g_user, ln_b_user, ln_g_item, ln_b_item, out);
}

// Round 10
// 613.719 us; speedup vs baseline: 1.0805x; 1.0805x over previous
//
#include <hip/hip_runtime.h>

#define NN 50000
#define DD 256
#define HH 8
#define EE 500000
#define INV_SQRT_DK 0.17677669529663687f

typedef __attribute__((ext_vector_type(8))) short bf16x8;   // 8 bf16 = 4 VGPRs
typedef __attribute__((ext_vector_type(4))) float f32x4;

__device__ __forceinline__ unsigned short f2bf(float f) {
    unsigned int u = __float_as_uint(f);
    u = (u + 0x7FFFu + ((u >> 16) & 1u)) >> 16;   // round-to-nearest-even
    return (unsigned short)u;
}
__device__ __forceinline__ float bf2f(unsigned short u) {
    return __uint_as_float(((unsigned int)u) << 16);
}
__device__ __forceinline__ float bflo(unsigned int u) {     // low bf16 of dword
    return __uint_as_float(u << 16);
}
__device__ __forceinline__ float bfhi(unsigned int u) {     // high bf16 of dword
    return __uint_as_float(u & 0xFFFF0000u);
}

// ---------------------------------------------------------------------------
// MEGA-PREP, three block ranges:
//   [0, 25000)        fp32->bf16 conversion of both feature tensors
//   [25000, 27056)    weight transforms (257 x 8 tuples)
//   [27056, 30964)    degree histogram; atomic RETURN VALUE = within-dst
//                     sequence number -> eseq[e] (makes scatter atomic-free)
// cnt must be zeroed beforehand.
__global__ __launch_bounds__(256) void prep_kernel(const float* __restrict__ Xu,
                                                   const float* __restrict__ Xi,
                                                   unsigned short* __restrict__ Yu,
                                                   unsigned short* __restrict__ Yi,
                                                   const float* __restrict__ Wk_u, const float* __restrict__ bk_u,
                                                   const float* __restrict__ att_ui_,
                                                   const float* __restrict__ Wv_u, const float* __restrict__ bv_u,
                                                   const float* __restrict__ msg_ui_,
                                                   const float* __restrict__ Wk_i, const float* __restrict__ bk_i,
                                                   const float* __restrict__ att_iu_,
                                                   const float* __restrict__ Wv_i, const float* __restrict__ bv_i,
                                                   const float* __restrict__ msg_iu_,
                                                   const float* __restrict__ Wq_u, const float* __restrict__ bq_u,
                                                   const float* __restrict__ Wq_i, const float* __restrict__ bq_i,
                                                   const float* __restrict__ Wa_u, const float* __restrict__ Wa_i,
                                                   unsigned short* __restrict__ BTu, float* __restrict__ beffU,
                                                   unsigned short* __restrict__ BTi, float* __restrict__ beffI,
                                                   unsigned short* __restrict__ WaTu, unsigned short* __restrict__ WaTi,
                                                   const int* __restrict__ dst_ui, const int* __restrict__ dst_iu,
                                                   int* __restrict__ cnt, unsigned short* __restrict__ eseq) {
    int blk = blockIdx.x;
    if (blk < 25000) {
        // ---- fp32 -> bf16 feature conversion ----
        const size_t ND = (size_t)NN * DD;
        size_t i = ((size_t)blk * 256 + threadIdx.x) * 4;
        const float* X = Xu; unsigned short* Y = Yu;
        if (i >= ND) { X = Xi; Y = Yi; i -= ND; }
        float4 v = *(const float4*)&X[i];
        ushort4 o;
        o.x = f2bf(v.x); o.y = f2bf(v.y); o.z = f2bf(v.z); o.w = f2bf(v.w);
        *(ushort4*)&Y[i] = o;
        return;
    }
    if (blk >= 27056) {
        // ---- histogram + sequence capture ----
        int e = (blk - 27056) * 256 + threadIdx.x;
        int d;
        if (e < EE) d = dst_ui[e];
        else if (e < 2 * EE) d = NN + dst_iu[e - EE];
        else return;
        int seq = atomicAdd(&cnt[d], 1);
        eseq[e] = (unsigned short)seq;
        return;
    }
    // ---- weight transforms ----
    int wblk = blk - 25000;
    int y = wblk / 257, x = wblk % 257;
    if (y < 4) {
        const float* W = (y == 0) ? Wk_u : (y == 1) ? Wv_u : (y == 2) ? Wk_i : Wv_i;
        const float* b = (y == 0) ? bk_u : (y == 1) ? bv_u : (y == 2) ? bk_i : bv_i;
        const float* T = (y == 0) ? att_ui_ : (y == 1) ? msg_ui_ : (y == 2) ? att_iu_ : msg_iu_;
        unsigned short* WT = (y < 2) ? BTu : BTi;
        float* be = (y < 2) ? beffU : beffI;
        int j = threadIdx.x;
        int h = j >> 5, jj = j & 31;
        int pj = ((j >> 2) << 3) + (j & 3) + ((y & 1) ? 4 : 0);   // interleaved KV row
        const float* Th = T + h * 1024;
        if (x < 256) {
            int c = x;
            float acc = 0.f;
            #pragma unroll 8
            for (int i = 0; i < 32; ++i) acc += W[c * 256 + h * 32 + i] * Th[i * 32 + jj];
            WT[pj * 256 + c] = f2bf(acc);
        } else {
            float acc = 0.f;
            #pragma unroll 8
            for (int i = 0; i < 32; ++i) acc += b[h * 32 + i] * Th[i * 32 + jj];
            be[pj] = acc;
        }
    } else if (x < 256) {
        int yy = y - 4;
        const float* W = (yy == 0) ? Wq_u : (yy == 1) ? Wq_i : (yy == 2) ? Wa_u : Wa_i;
        unsigned short* WT = (yy == 0) ? BTu + 512 * 256 : (yy == 1) ? BTi + 512 * 256 : (yy == 2) ? WaTu : WaTi;
        int k = x, n = threadIdx.x;
        WT[n * 256 + k] = f2bf(W[k * 256 + n]);
        if (k == 0 && yy < 2) {
            float* be = (yy == 0) ? beffU : beffI;
            const float* bq = (yy == 0) ? bq_u : bq_i;
            be[512 + n] = bq[n];
        }
    }
}

// ---------------------------------------------------------------------------
__global__ __launch_bounds__(256) void alloc_kernel(const int* __restrict__ cnt,
                                                    int* __restrict__ start,
                                                    int* __restrict__ ctr) {
    int y = blockIdx.y;
    int i = blockIdx.x * 256 + threadIdx.x;
    int idx = y * NN + i;
    int v = (i < NN) ? cnt[idx] : 0;
    int lane = threadIdx.x & 63;
    int pre = v;
    #pragma unroll
    for (int o = 1; o < 64; o <<= 1) {
        int u = __shfl_up(pre, o, 64);
        if (lane >= o) pre += u;
    }
    int wsum = __shfl(pre, 63, 64);
    int base = 0;
    if (lane == 63) base = atomicAdd(&ctr[y], wsum);
    base = __shfl(base, 63, 64);
    if (i < NN) start[idx] = y * EE + base + pre - v;
}

// ---------------------------------------------------------------------------
// ATOMIC-FREE scatter: position = start[d] + eseq[e] (seq captured in prep).
__global__ void scatter_kernel(const int* __restrict__ dst_ui, const int* __restrict__ src_ui,
                               const int* __restrict__ dst_iu, const int* __restrict__ src_iu,
                               const int* __restrict__ start, const unsigned short* __restrict__ eseq,
                               unsigned short* __restrict__ srcid) {
    int e = blockIdx.x * blockDim.x + threadIdx.x;
    int d, s;
    if (e < EE) { d = dst_ui[e]; s = src_ui[e]; }
    else if (e < 2 * EE) { d = NN + dst_iu[e - EE]; s = src_iu[e - EE]; }
    else return;
    int pos = start[d] + (int)eseq[e];
    srcid[pos] = (unsigned short)s;
}

// ---------------------------------------------------------------------------
// C[M,768] = A_bf16[M,256] @ BT_bf16 + beff.   (restored R7 version — best
// measured; the R9 fp32-A/depth-2 variant regressed: pack8 VALU on the
// staging critical path + VGPR/occupancy drop + 2x A-fetch bytes.)
// BT rows 0..511 pre-permuted -> cols 0..511 ARE the interleaved KV layout.
// 2-phase double-buffered pipeline, one barrier per K-step.
// 1D grid 4692 with bijective XCD swizzle (m204), bn fastest -> the 6 blocks
// sharing an A-panel run on the SAME XCD -> A re-reads are L2 hits.
// Epilogue: two 64-row halves staged via LDS (stride 136), ushort8 stores.
__global__ __launch_bounds__(256) void gemm_kvq(const unsigned short* __restrict__ Au,
                                                const unsigned short* __restrict__ Ai,
                                                const unsigned short* __restrict__ BTu,
                                                const unsigned short* __restrict__ BTi,
                                                const float* __restrict__ beffU,
                                                const float* __restrict__ beffI,
                                                unsigned short* __restrict__ KVu,
                                                unsigned short* __restrict__ KVi,
                                                unsigned short* __restrict__ Qu,
                                                unsigned short* __restrict__ Qi) {
    __shared__ __align__(16) char smem[40960];   // 2 x (As 10240 | Bs 10240); epilogue reuses
    bf16x8* As0 = (bf16x8*)smem;
    bf16x8* Bs0 = (bf16x8*)(smem + 10240);
    bf16x8* As1 = (bf16x8*)(smem + 20480);
    bf16x8* Bs1 = (bf16x8*)(smem + 30720);
    // ---- XCD-bijective swizzle: nwg = 4692 = 8*586 + 4 ----
    int bsw = blockIdx.x;
    int xcd = bsw & 7, sidx = bsw >> 3;
    int wg = (xcd < 4 ? xcd * 587 : 2348 + (xcd - 4) * 586) + sidx;
    int bni = wg % 6; int rest = wg / 6;
    int bmi = rest % 391; int z = rest / 391;
    const unsigned short* A = z ? Ai : Au;
    const unsigned short* BT = z ? BTi : BTu;
    const float* beff = z ? beffI : beffU;
    unsigned short* KV = z ? KVi : KVu;
    unsigned short* Qb = z ? Qi : Qu;
    int bm = bmi * 128, bn = bni * 128;
    int tid = threadIdx.x;
    int lane = tid & 63, w = tid >> 6;
    int wm = (w & 1) * 64, wn = (w >> 1) * 64;
    int m16 = lane & 15, q = lane >> 4;

    // staging geometry: thread covers (row0, off) and (row1 = row0+64, off)
    int row0 = tid >> 2, off = tid & 3;
    int row1 = row0 + 64;
    int gr0 = bm + row0, gr1 = bm + row1;
    const bool val0 = gr0 < NN, val1 = gr1 < NN;
    const unsigned short* pA0 = &A[(size_t)gr0 * 256 + off * 8];
    const unsigned short* pA1 = &A[(size_t)gr1 * 256 + off * 8];
    const unsigned short* pB0 = &BT[(size_t)(bn + row0) * 256 + off * 8];
    const unsigned short* pB1 = &BT[(size_t)(bn + row1) * 256 + off * 8];

    f32x4 acc[4][4] = {};
    const bf16x8 zz = {};
    // prologue: tile 0 -> LDS buf0; tile 1 -> regs
    bf16x8 ra0 = zz, ra1 = zz, rb0, rb1;
    if (val0) ra0 = *(const bf16x8*)pA0;
    if (val1) ra1 = *(const bf16x8*)pA1;
    rb0 = *(const bf16x8*)pB0;
    rb1 = *(const bf16x8*)pB1;
    As0[row0 * 5 + off] = ra0; As0[row1 * 5 + off] = ra1;
    Bs0[row0 * 5 + off] = rb0; Bs0[row1 * 5 + off] = rb1;
    ra0 = zz; ra1 = zz;
    if (val0) ra0 = *(const bf16x8*)(pA0 + 32);
    if (val1) ra1 = *(const bf16x8*)(pA1 + 32);
    rb0 = *(const bf16x8*)(pB0 + 32);
    rb1 = *(const bf16x8*)(pB1 + 32);
    __syncthreads();
    #pragma unroll
    for (int ks = 0; ks < 8; ++ks) {
        bf16x8* Ac = (ks & 1) ? As1 : As0;
        bf16x8* Bc = (ks & 1) ? Bs1 : Bs0;
        bf16x8* An = (ks & 1) ? As0 : As1;
        bf16x8* Bn = (ks & 1) ? Bs0 : Bs1;
        if (ks < 7) {                                   // stage tile ks+1 (regs -> other buf)
            An[row0 * 5 + off] = ra0; An[row1 * 5 + off] = ra1;
            Bn[row0 * 5 + off] = rb0; Bn[row1 * 5 + off] = rb1;
        }
        if (ks < 6) {                                   // issue tile ks+2 global loads
            int k0 = (ks + 2) * 32;
            ra0 = zz; ra1 = zz;
            if (val0) ra0 = *(const bf16x8*)(pA0 + k0);
            if (val1) ra1 = *(const bf16x8*)(pA1 + k0);
            rb0 = *(const bf16x8*)(pB0 + k0);
            rb1 = *(const bf16x8*)(pB1 + k0);
        }
        bf16x8 af[4], bfr[4];
        #pragma unroll
        for (int i = 0; i < 4; ++i) af[i] = Ac[(wm + 16 * i + m16) * 5 + q];
        #pragma unroll
        for (int j = 0; j < 4; ++j) bfr[j] = Bc[(wn + 16 * j + m16) * 5 + q];
        #pragma unroll
        for (int i = 0; i < 4; ++i)
            #pragma unroll
            for (int j = 0; j < 4; ++j)
                acc[i][j] = __builtin_amdgcn_mfma_f32_16x16x32_bf16(af[i], bfr[j], acc[i][j], 0, 0, 0);
        __syncthreads();
    }
    // ---- epilogue: two 64-row halves staged via LDS, coalesced 16B stores ----
    const bool isKV = (bn < 512);
    unsigned short* dstb = isKV ? KV : Qb;
    const int rowlen = isKV ? 512 : 256;
    const int coloff = isKV ? bn : (bn - 512);
    unsigned short* Cs = (unsigned short*)smem;   // 64*136 = 8704 ushorts = 17408B
    #pragma unroll
    for (int half = 0; half < 2; ++half) {
        if ((w & 1) == half) {                    // waves owning rows [half*64, half*64+64)
            #pragma unroll
            for (int i = 0; i < 4; ++i) {
                int rloc = 16 * i + q * 4;        // local row within half (wm == half*64)
                #pragma unroll
                for (int j = 0; j < 4; ++j) {
                    int cl = wn + 16 * j + m16;
                    float bv = beff[bn + cl];
                    #pragma unroll
                    for (int r = 0; r < 4; ++r)
                        Cs[(rloc + r) * 136 + cl] = f2bf(acc[i][j][r] + bv);
                }
            }
        }
        __syncthreads();
        #pragma unroll
        for (int it = 0; it < 4; ++it) {
            int idx = it * 256 + tid;
            int row = idx >> 4, seg = idx & 15;
            int gr = bm + half * 64 + row;
            if (gr < NN) {
                bf16x8 v = *(const bf16x8*)&Cs[row * 136 + seg * 8];
                *(bf16x8*)&dstb[(size_t)gr * rowlen + coloff + seg * 8] = v;
            }
        }
        __syncthreads();
    }
}

// ---------------------------------------------------------------------------
// FUSED out-projection + skip-gate + layernorm.
// C[128,256] = A_bf16 @ WaT + ba; out = LN(C*alpha + h*(1-alpha)).
// 512 threads = 8 waves; wave w owns rows [16w,16w+16) x ALL 256 cols.
// grid (391, 2): y = ntype (0 user -> out[0], 1 item -> out[ND]).
__global__ __launch_bounds__(512) void gemm_ln(const unsigned short* __restrict__ A0,
                                               const unsigned short* __restrict__ A1,
                                               const unsigned short* __restrict__ BT0,
                                               const unsigned short* __restrict__ BT1,
                                               const float* __restrict__ ba0,
                                               const float* __restrict__ ba1,
                                               const float* __restrict__ h0,
                                               const float* __restrict__ h1,
                                               const float* __restrict__ skp0,
                                               const float* __restrict__ skp1,
                                               const float* __restrict__ g0, const float* __restrict__ be0,
                                               const float* __restrict__ g1, const float* __restrict__ be1,
                                               float* __restrict__ out) {
    __shared__ __align__(16) char smem[33280];   // staging 30720B | epilogue 32*260*4B
    bf16x8* As = (bf16x8*)smem;                  // 128*5 entries = 10240B
    bf16x8* Bs = (bf16x8*)(smem + 10240);        // 256*5 entries = 20480B
    float* Es = (float*)smem;                    // epilogue: [32][260]
    int z = blockIdx.y;
    const unsigned short* A = z ? A1 : A0;
    const unsigned short* BT = z ? BT1 : BT0;
    const float* ba = z ? ba1 : ba0;
    const float* hb = z ? h1 : h0;
    const float* skp = z ? skp1 : skp0;
    const float* g = z ? g1 : g0;
    const float* bb = z ? be1 : be0;
    float* o = out + (z ? (size_t)NN * DD : 0);

    int bm = blockIdx.x * 128;
    int tid = threadIdx.x;
    int lane = tid & 63, w = tid >> 6;           // w in [0,8)
    int m16 = lane & 15, q = lane >> 4;
    f32x4 acc[16] = {};
    for (int k0 = 0; k0 < 256; k0 += 32) {
        {   // A: 128 rows x 4 chunks -> one vec8 per thread
            int row = tid >> 2, ch = tid & 3;
            int gr = bm + row;
            bf16x8 va = {};
            if (gr < NN) va = *(const bf16x8*)&A[(size_t)gr * 256 + k0 + ch * 8];
            As[row * 5 + ch] = va;
        }
        #pragma unroll
        for (int cc = 0; cc < 2; ++cc) {         // B: 256 rows x 4 chunks -> two per thread
            int idx = tid + cc * 512;
            int n = idx >> 2, ch = idx & 3;
            Bs[n * 5 + ch] = *(const bf16x8*)&BT[(size_t)n * 256 + k0 + ch * 8];
        }
        __syncthreads();
        bf16x8 af = As[(w * 16 + m16) * 5 + q];
        #pragma unroll
        for (int jh = 0; jh < 2; ++jh) {
            bf16x8 bfr[8];
            #pragma unroll
            for (int jj = 0; jj < 8; ++jj) bfr[jj] = Bs[((jh * 8 + jj) * 16 + m16) * 5 + q];
            #pragma unroll
            for (int jj = 0; jj < 8; ++jj)
                acc[jh * 8 + jj] = __builtin_amdgcn_mfma_f32_16x16x32_bf16(af, bfr[jj], acc[jh * 8 + jj], 0, 0, 0);
        }
        __syncthreads();
    }
    // ---- fused epilogue: 4 quarters of 32 rows ----
    float alpha = 1.f / (1.f + __expf(-skp[0]));
    float am1 = 1.f - alpha;
    float4 ba4 = *(const float4*)&ba[lane * 4];
    float4 g4 = *(const float4*)&g[lane * 4];
    float4 b4 = *(const float4*)&bb[lane * 4];
    #pragma unroll
    for (int p = 0; p < 4; ++p) {
        if ((w >> 1) == p) {                     // stage this quarter's acc (f32)
            int rbase = (w & 1) * 16 + 4 * q;
            #pragma unroll
            for (int j = 0; j < 16; ++j)
                #pragma unroll
                for (int rr = 0; rr < 4; ++rr)
                    Es[(rbase + rr) * 260 + 16 * j + m16] = acc[j][rr];
        }
        __syncthreads();
        #pragma unroll
        for (int rrr = 0; rrr < 4; ++rrr) {
            int lrow = w * 4 + rrr;              // 0..31
            int gr = bm + 32 * p + lrow;
            if (gr < NN) {
                float4 tm = *(const float4*)&Es[lrow * 260 + lane * 4];
                float4 hh = *(const float4*)&hb[(size_t)gr * 256 + lane * 4];
                float x0 = (tm.x + ba4.x) * alpha + hh.x * am1;
                float x1 = (tm.y + ba4.y) * alpha + hh.y * am1;
                float x2 = (tm.z + ba4.z) * alpha + hh.z * am1;
                float x3 = (tm.w + ba4.w) * alpha + hh.w * am1;
                float s = x0 + x1 + x2 + x3;
                #pragma unroll
                for (int off = 32; off > 0; off >>= 1) s += __shfl_xor(s, off, 64);
                float mean = s * (1.f / 256.f);
                float d0 = x0 - mean, d1 = x1 - mean, d2 = x2 - mean, d3 = x3 - mean;
                float s2 = d0 * d0 + d1 * d1 + d2 * d2 + d3 * d3;
                #pragma unroll
                for (int off = 32; off > 0; off >>= 1) s2 += __shfl_xor(s2, off, 64);
                float rstd = rsqrtf(s2 * (1.f / 256.f) + 1e-5f);
                float4 r;
                r.x = d0 * rstd * g4.x + b4.x;
                r.y = d1 * rstd * g4.y + b4.y;
                r.z = d2 * rstd * g4.z + b4.z;
                r.w = d3 * rstd * g4.w + b4.w;
                *(float4*)&o[(size_t)gr * 256 + lane * 4] = r;
            }
        }
        __syncthreads();
    }
}

// ---------------------------------------------------------------------------
// Fused score+softmax+aggregate, ONE WAVE per dst node, 4 elems per lane.
// srcid is ushort (src < 50000 < 65536).  Per 64-edge chunk, srcids come from
// one coalesced 2B/lane load (broadcast by __shfl); KV rows prefetched 4-deep
// into statically-indexed registers.
// grid 25000 x 256 (4 waves = 4 dst slots per block; slots >= NN are etype iu).
__global__ __launch_bounds__(256) void fused_agg(const int* __restrict__ start,
                                                 const int* __restrict__ cnt,
                                                 const unsigned short* __restrict__ srcid,
                                                 const unsigned short* __restrict__ Qi,
                                                 const unsigned short* __restrict__ Qu,
                                                 const unsigned short* __restrict__ KVu,
                                                 const unsigned short* __restrict__ KVi,
                                                 const float* __restrict__ pri_ui,
                                                 const float* __restrict__ pri_iu,
                                                 unsigned short* __restrict__ tI16,
                                                 unsigned short* __restrict__ tU16) {
    int w = threadIdx.x >> 6;
    int lane = threadIdx.x & 63;
    int b = blockIdx.x * 4 + w;
    bool second = (b >= NN);
    int d = second ? b - NN : b;
    const unsigned short* Q = second ? Qu : Qi;
    const unsigned short* KV = second ? KVi : KVu;
    const float* pri = second ? pri_iu : pri_ui;
    unsigned short* T = second ? tU16 : tI16;

    int h = lane >> 3;
    float sscale = pri[h] * INV_SQRT_DK;
    ushort4 q4 = *(const ushort4*)&Q[(size_t)d * 256 + lane * 4];
    float qx = bf2f(q4.x), qy = bf2f(q4.y), qz = bf2f(q4.z), qw = bf2f(q4.w);

    int p0 = start[b], n = cnt[b];
    float a0 = 0.f, a1 = 0.f, a2 = 0.f, a3 = 0.f, l = 0.f;

#define LDKV(idx) (*(const uint4*)&KV[(size_t)__shfl(myS, (idx), 64) * 512 + lane * 8])
#define PROC(kv) { \
        float sc = qx * bflo(kv.x) + qy * bfhi(kv.x) + qz * bflo(kv.y) + qw * bfhi(kv.y); \
        sc += __shfl_xor(sc, 1, 8); \
        sc += __shfl_xor(sc, 2, 8); \
        sc += __shfl_xor(sc, 4, 8); \
        float wgt = __expf(sc * sscale); \
        a0 += wgt * bflo(kv.z); \
        a1 += wgt * bfhi(kv.z); \
        a2 += wgt * bflo(kv.w); \
        a3 += wgt * bfhi(kv.w); \
        l += wgt; }

    for (int base = 0; base < n; base += 64) {
        int rem = n - base; if (rem > 64) rem = 64;
        int myS = (lane < rem) ? (int)srcid[p0 + base + lane] : 0;
        uint4 k0 = {}, k1 = {}, k2 = {}, k3 = {};
        if (0 < rem) k0 = LDKV(0);
        if (1 < rem) k1 = LDKV(1);
        if (2 < rem) k2 = LDKV(2);
        if (3 < rem) k3 = LDKV(3);
        int t = 0;
        for (; t + 4 <= rem; t += 4) {
            PROC(k0); if (t + 4 < rem) k0 = LDKV(t + 4);
            PROC(k1); if (t + 5 < rem) k1 = LDKV(t + 5);
            PROC(k2); if (t + 6 < rem) k2 = LDKV(t + 6);
            PROC(k3); if (t + 7 < rem) k3 = LDKV(t + 7);
        }
        if (t < rem)     PROC(k0);
        if (t + 1 < rem) PROC(k1);
        if (t + 2 < rem) PROC(k2);
    }
#undef LDKV
#undef PROC

    float inv = (l > 0.f) ? 1.f / l : 0.f;
    ushort4 o;
    o.x = f2bf(a0 * inv); o.y = f2bf(a1 * inv);
    o.z = f2bf(a2 * inv); o.w = f2bf(a3 * inv);
    *(ushort4*)&T[(size_t)d * 256 + lane * 4] = o;
}

// ---------------------------------------------------------------------------
extern "C" void kernel_launch(void* const* d_in, const int* in_sizes, int n_in,
                              void* d_out, int out_size, void* d_ws, size_t ws_size,
                              hipStream_t stream) {
    const float* h_user  = (const float*)d_in[0];
    const float* h_item  = (const float*)d_in[1];
    const int*   src_ui  = (const int*)d_in[2];
    const int*   dst_ui  = (const int*)d_in[3];
    const int*   src_iu  = (const int*)d_in[4];
    const int*   dst_iu  = (const int*)d_in[5];
    const float* Wk_user = (const float*)d_in[6];
    const float* bk_user = (const float*)d_in[7];
    const float* Wq_user = (const float*)d_in[8];
    const float* bq_user = (const float*)d_in[9];
    const float* Wv_user = (const float*)d_in[10];
    const float* bv_user = (const float*)d_in[11];
    const float* Wa_user = (const float*)d_in[12];
    const float* ba_user = (const float*)d_in[13];
    const float* ln_g_user = (const float*)d_in[14];
    const float* ln_b_user = (const float*)d_in[15];
    const float* skip_user = (const float*)d_in[16];
    const float* Wk_item = (const float*)d_in[17];
    const float* bk_item = (const float*)d_in[18];
    const float* Wq_item = (const float*)d_in[19];
    const float* bq_item = (const float*)d_in[20];
    const float* Wv_item = (const float*)d_in[21];
    const float* bv_item = (const float*)d_in[22];
    const float* Wa_item = (const float*)d_in[23];
    const float* ba_item = (const float*)d_in[24];
    const float* ln_g_item = (const float*)d_in[25];
    const float* ln_b_item = (const float*)d_in[26];
    const float* skip_item = (const float*)d_in[27];
    const float* pri_ui = (const float*)d_in[28];
    const float* att_ui = (const float*)d_in[29];
    const float* msg_ui = (const float*)d_in[30];
    const float* pri_iu = (const float*)d_in[31];
    const float* att_iu = (const float*)d_in[32];
    const float* msg_iu = (const float*)d_in[33];
    float* out = (float*)d_out;

    const size_t ND = (size_t)NN * DD;

    // ---- workspace carve (~210 MB, with aliasing) ----
    unsigned short* up = (unsigned short*)d_ws;
    unsigned short* KVu = up;  up += (size_t)NN * 512;   // interleaved K|V per user node
    unsigned short* KVi = up;  up += (size_t)NN * 512;
    unsigned short* Qu  = up;  up += ND;
    unsigned short* Qi  = up;  up += ND;
    unsigned short* hU16 = up; up += ND;                 // bf16 features; reused as t-bufs
    unsigned short* hI16 = up; up += ND;
    unsigned short* BTu = up;  up += 768 * 256;
    unsigned short* BTi = up;  up += 768 * 256;
    unsigned short* WaTu = up; up += 65536;
    unsigned short* WaTi = up; up += 65536;
    float* fp = (float*)up;
    float* beffU = fp; fp += 768;
    float* beffI = fp; fp += 768;
    int* ip = (int*)fp;
    int* cnt   = ip; ip += 2 * NN;     // cnt+ctr contiguous: single memset
    int* ctr   = ip; ip += 2;
    int* start = ip; ip += 2 * NN;
    unsigned short* srcid = (unsigned short*)ip;  ip += EE;      // 2*EE ushorts
    unsigned short* eseq  = (unsigned short*)ip;                 // 2*EE ushorts
    // aliases (lifetimes disjoint in stream order):
    unsigned short* tU16 = hU16;
    unsigned short* tI16 = hI16;

    const int eb = (EE + 255) / 256;   // 1954

    // ---- prep: memset, conv+weights+hist (one mega-kernel), alloc, scatter --
    hipMemsetAsync(cnt, 0, (2 * NN + 2) * sizeof(int), stream);
    prep_kernel<<<25000 + 2056 + 2 * eb, 256, 0, stream>>>(
        h_user, h_item, hU16, hI16,
        Wk_user, bk_user, att_ui, Wv_user, bv_user, msg_ui,
        Wk_item, bk_item, att_iu, Wv_item, bv_item, msg_iu,
        Wq_user, bq_user, Wq_item, bq_item, Wa_user, Wa_item,
        BTu, beffU, BTi, beffI, WaTu, WaTi,
        dst_ui, dst_iu, cnt, eseq);
    alloc_kernel<<<dim3(196, 2), 256, 0, stream>>>(cnt, start, ctr);
    scatter_kernel<<<2 * eb, 256, 0, stream>>>(dst_ui, src_ui, dst_iu, src_iu,
                                               start, eseq, srcid);

    // ---- projections: one dispatch, both ntypes, N=768 (K|V|Q) ----
    gemm_kvq<<<4692, 256, 0, stream>>>(hU16, hI16, BTu, BTi, beffU, beffI,
                                       KVu, KVi, Qu, Qi);

    // ---- fused edge-softmax aggregation, both etypes ----
    fused_agg<<<25000, 256, 0, stream>>>(start, cnt, srcid, Qi, Qu, KVu, KVi,
                                         pri_ui, pri_iu, tI16, tU16);

    // ---- FUSED out-projection + skip-gate + layernorm ----
    gemm_ln<<<dim3(391, 2), 512, 0, stream>>>(tU16, tI16, WaTu, WaTi, ba_user, ba_item,
                                              h_user, h_item, skip_user, skip_item,
                                              ln_g_user, ln_b_user, ln_g_item, ln_b_item, out);
}